// Round 9
// baseline (4350.327 us; speedup 1.0000x reference)
//
#include <hip/hip_runtime.h>
#include <hip/hip_fp16.h>
#include <math.h>

#define B_ 64
#define T_ 700
#define U_ 400
#define FR_LS 13312                   // dwords per (layer,slot): 4 bt x 13 kc x 256

typedef _Float16 half8 __attribute__((ext_vector_type(8)));
typedef float float4v __attribute__((ext_vector_type(4)));

union AFrag { unsigned u[4]; half8 h; };

// ---- agent-scope (cross-XCD coherent) helpers ----
__device__ __forceinline__ unsigned agloadu(const unsigned* p) {
    return __hip_atomic_load(p, __ATOMIC_RELAXED, __HIP_MEMORY_SCOPE_AGENT);
}
__device__ __forceinline__ void agstoreu(unsigned* p, unsigned v) {
    __hip_atomic_store(p, v, __ATOMIC_RELAXED, __HIP_MEMORY_SCOPE_AGENT);
}
__device__ __forceinline__ float sig_(float v) {
    return __builtin_amdgcn_rcpf(1.f + __expf(-v));
}
__device__ __forceinline__ float tanh_(float v) {
    return 1.f - 2.f * __builtin_amdgcn_rcpf(__expf(2.f * v) + 1.f);
}
__device__ __forceinline__ void waitctr(const unsigned* f, unsigned target) {
    while (agloadu(f) < target) __builtin_amdgcn_s_sleep(2);
}
__device__ __forceinline__ unsigned f16u(float v) {
    union { _Float16 f; unsigned short s; } cv; cv.f = (_Float16)v; return (unsigned)cv.s;
}

// Parity-tagged fragment read: sloppy low-volume probe (1 dword/lane, sleep-backed),
// then batched verify over 13 chunks x 4 dwords. Verify is authoritative; wrap-parity
// is ABA-safe (opposite parity was observed at these addresses DEPTH steps earlier,
// and lagged counters bound producer lead to < 2*DEPTH). Every dword incl. K-pad is
// rewritten each step (per-wave pad writers in blk 49/149/249).
template<int SL>
__device__ __forceinline__ void pollfrag13(const unsigned* __restrict__ base,
                                           const unsigned par,
                                           AFrag* __restrict__ a, const int lane)
{
    {   // probe: 1 dword/lane spread across all 13 chunks (no correctness role)
        const unsigned* pp = base + (lane % 13) * 256 + ((lane * 37) & 255);
        while (!__all((int)(((agloadu(pp) ^ par) & 1u) == 0u)))
            __builtin_amdgcn_s_sleep(SL);
    }
    unsigned pend = 0x1FFFu;
    do {
#pragma unroll
        for (int ck = 0; ck < 13; ++ck) if ((pend >> ck) & 1) {
#pragma unroll
            for (int d = 0; d < 4; ++d)
                a[ck].u[d] = agloadu(base + ck * 256 + d * 64 + lane);
        }
#pragma unroll
        for (int ck = 0; ck < 13; ++ck) if ((pend >> ck) & 1) {
            const unsigned m = (a[ck].u[0] ^ par) | (a[ck].u[1] ^ par)
                             | (a[ck].u[2] ^ par) | (a[ck].u[3] ^ par);
            if (__all((int)((m & 1u) == 0u))) pend &= ~(1u << ck);
        }
        if (pend) __builtin_amdgcn_s_sleep(1);
    } while (pend);
}

//  blocks 0..49   : layer 0, 8 units (32 gate-cols), A = h0[t-1]
//  blocks 50..149 : layer 1, 4 units, A = [h0[t] ; h1[t-1]]
//  blocks 150..249: layer 2, 4 units, A = [h1[t] ; h2[t-1]]
//  block 250      : output projection h2[t] @ Wd + bd
//  ALL edges parity-polled (no data-ready flags, no vmcnt drain, no RMW, no
//  per-step __syncthreads — each wave is an independent b-tile pipeline).
//  Anti-overwrite: 12 lagged single-writer counters D[layer][bt], bumped by the
//  first block of the consumer layer (blk 50/150/250), per wave.
template<int DEPTH>
__global__ void __launch_bounds__(256, 1)
lstm_pb(const float* __restrict__ x,
        const float* __restrict__ Wx0,
        const float* __restrict__ Wx1,
        const float* __restrict__ Wx2,
        const float* __restrict__ Wh,
        const float* __restrict__ bias,
        const float* __restrict__ pi,
        const float* __restrict__ pf,
        const float* __restrict__ po,
        const float* __restrict__ Wd,
        const float* __restrict__ bd,
        float* __restrict__ out,
        unsigned* __restrict__ ws)
{
    __shared__ alignas(16) _Float16 wlds[26 * 512];   // 26.6 KB B-frags [ck][lane][8]
    __shared__ alignas(16) float zlds[4 * 528];       // 8.4 KB per-wave z tiles
    __shared__ float gc[160];                          // gate constants

    unsigned* Dc    = ws;          // [3][4] counters, stride 32 dwords (128 B lines)
    unsigned* frag0 = ws + 512;    // [3][DEPTH][FR_LS], init 0xFF (parity 1)

    const int blk  = blockIdx.x;
    const int tid  = threadIdx.x;
    const int lane = tid & 63;
    const int wv   = tid >> 6;

    int layer, u0;
    if      (blk < 50)  { layer = 0; u0 = blk * 8; }
    else if (blk < 150) { layer = 1; u0 = (blk - 50) * 4; }
    else if (blk < 250) { layer = 2; u0 = (blk - 150) * 4; }
    else                { layer = 3; u0 = 0; }

    const bool padw = (blk == 49) || (blk == 149) || (blk == 249);

    // ---- one-time: stage weights into LDS in B-fragment order ----
    {
        const float* __restrict__ Wxl = (layer == 1) ? Wx1 : Wx2;
        for (int i = tid; i < 26 * 64; i += 256) {
            const int ln = i & 63, ck = i >> 6;
            const int q = ln >> 4, nn = ln & 15;
            float vals[8];
#pragma unroll
            for (int j = 0; j < 8; ++j) {
                const int kc = ck % 13;
                const int k = kc * 32 + q * 8 + j;
                float v = 0.f;
                if (k < 400) {
                    if (layer == 0) {
                        const int col32 = (ck / 13) * 16 + nn;
                        const int gcol = (col32 >> 3) * U_ + u0 + (col32 & 7);
                        v = Wh[(size_t)k * 1600 + gcol];
                    } else if (layer < 3) {
                        const int gcol = (nn >> 2) * U_ + u0 + (nn & 3);
                        v = (ck >= 13) ? Wh[((size_t)layer * U_ + k) * 1600 + gcol]
                                       : Wxl[(size_t)k * 1600 + gcol];
                    } else {
                        if (ck < 13 && nn < 3) v = Wd[k * 3 + nn];
                    }
                }
                vals[j] = v;
            }
#pragma unroll
            for (int j = 0; j < 8; ++j)
                wlds[ck * 512 + ln * 8 + j] = (_Float16)vals[j];
        }
        if (layer == 0) {
            if (tid < 128) {
                const int col32 = tid >> 2, comp = tid & 3;
                const int gcol = (col32 >> 3) * U_ + u0 + (col32 & 7);
                gc[tid] = (comp == 0) ? bias[gcol] : Wx0[(size_t)(comp - 1) * 1600 + gcol];
            } else if (tid < 152) {
                const int idx = tid - 128, ul = idx / 3, j = idx - ul * 3;
                const float* pp = (j == 0) ? pi : (j == 1) ? pf : po;
                gc[tid] = pp[u0 + ul];
            }
        } else if (layer < 3) {
            if (tid < 16) {
                gc[tid] = bias[layer * 1600 + (tid >> 2) * U_ + u0 + (tid & 3)];
            } else if (tid < 28) {
                const int idx = tid - 16, ul = idx / 3, j = idx - ul * 3;
                const float* pp = (j == 0) ? pi : (j == 1) ? pf : po;
                gc[tid] = pp[layer * U_ + u0 + ul];
            }
        } else {
            if (tid < 3) gc[tid] = bd[tid];
        }
    }
    __syncthreads();   // wlds/gc ready; the ONLY barrier — steady loop is barrier-free

    const int wvz   = wv * 528;
    const int b_loc = lane & 15;
    const int quad  = lane >> 4;
    float cst[2] = {0.f, 0.f};

    for (int t = 0; t < T_; ++t) {
        const int sw = t % DEPTH;
        const int sr = (t + DEPTH - 1) % DEPTH;
        const unsigned pI = (unsigned)((t / DEPTH) & 1);          // parity written at t
        const unsigned pO = (unsigned)(((t - 1) / DEPTH) & 1);    // parity of h[t-1] slot

        // x prefetch (L0), independent of sync
        float x0, x1, x2;
        if (layer == 0) {
            const size_t xb = (size_t)(wv * 16 + b_loc) * T_ + t;
            x0 = x[xb * 3 + 0]; x1 = x[xb * 3 + 1]; x2 = x[xb * 3 + 2];
        }

        // ---- parity-tagged edge polls (own first: arrives ~one phase earlier) ----
        AFrag aown[13], ainp[13];
        if (layer < 3) {
            if (t >= 1) {
                pollfrag13<1>(frag0 + (size_t)(layer * DEPTH + sr) * FR_LS + wv * 3328,
                              pO, aown, lane);
            } else {
#pragma unroll
                for (int ck = 0; ck < 13; ++ck)
#pragma unroll
                    for (int d = 0; d < 4; ++d) aown[ck].u[d] = 0u;
            }
            if (layer >= 1)
                pollfrag13<2>(frag0 + (size_t)((layer - 1) * DEPTH + sw) * FR_LS + wv * 3328,
                              pI, ainp, lane);
        } else {
            pollfrag13<2>(frag0 + (size_t)(2 * DEPTH + sw) * FR_LS + wv * 3328,
                          pI, aown, lane);
        }
        asm volatile("" ::: "memory");

        // ---- MFMA ----
        if (layer == 0) {
            float4v acc0 = {0.f, 0.f, 0.f, 0.f}, acc1 = {0.f, 0.f, 0.f, 0.f};
#pragma unroll
            for (int kc = 0; kc < 13; ++kc) {
                const half8 w0 = *(const half8*)&wlds[kc * 512 + lane * 8];
                const half8 w1 = *(const half8*)&wlds[(13 + kc) * 512 + lane * 8];
                acc0 = __builtin_amdgcn_mfma_f32_16x16x32_f16(aown[kc].h, w0, acc0, 0, 0, 0);
                acc1 = __builtin_amdgcn_mfma_f32_16x16x32_f16(aown[kc].h, w1, acc1, 0, 0, 0);
            }
#pragma unroll
            for (int r = 0; r < 4; ++r) {
                zlds[wvz + (quad * 4 + r) * 33 + b_loc] = acc0[r];
                zlds[wvz + (quad * 4 + r) * 33 + 16 + b_loc] = acc1[r];
            }
        } else if (layer < 3) {
            float4v acc = {0.f, 0.f, 0.f, 0.f};
#pragma unroll
            for (int kc = 0; kc < 13; ++kc) {
                const half8 wA = *(const half8*)&wlds[kc * 512 + lane * 8];          // Wx part
                const half8 wB = *(const half8*)&wlds[(13 + kc) * 512 + lane * 8];   // Wh part
                acc = __builtin_amdgcn_mfma_f32_16x16x32_f16(ainp[kc].h, wA, acc, 0, 0, 0);
                acc = __builtin_amdgcn_mfma_f32_16x16x32_f16(aown[kc].h, wB, acc, 0, 0, 0);
            }
#pragma unroll
            for (int r = 0; r < 4; ++r)
                zlds[wvz + (quad * 4 + r) * 33 + b_loc] = acc[r];
        } else {
            float4v acc = {0.f, 0.f, 0.f, 0.f};
#pragma unroll
            for (int kc = 0; kc < 13; ++kc) {
                const half8 w0 = *(const half8*)&wlds[kc * 512 + lane * 8];
                acc = __builtin_amdgcn_mfma_f32_16x16x32_f16(aown[kc].h, w0, acc, 0, 0, 0);
            }
            if (b_loc < 3) {
#pragma unroll
                for (int r = 0; r < 4; ++r)
                    out[((size_t)(wv * 16 + quad * 4 + r) * T_ + t) * 3 + b_loc] = acc[r] + gc[b_loc];
            }
        }

        // ---- lagged anti-overwrite wait (per-wave single-writer counters) ----
        if (layer < 3 && lane == 0 && t >= DEPTH)
            waitctr(Dc + (layer * 4 + wv) * 32, (unsigned)(t - DEPTH + 2));
        asm volatile("" ::: "memory");

        // ---- K-pad rewrite (per-wave, last block of each layer): parity-correct ----
        if (padw) {
            unsigned* fd = frag0 + (size_t)(layer * DEPTH + sw) * FR_LS + wv * 3328 + 12 * 256;
            agstoreu(fd + (lane >> 4) * 64 + 32 + (lane & 15), pI);   // q=2
            agstoreu(fd + (lane >> 4) * 64 + 48 + (lane & 15), pI);   // q=3
        }

        // ---- gates (fp32) + parity-tagged h store in A-fragment layout ----
        if (layer == 0) {
            unsigned* fr_dst = frag0 + (size_t)(0 * DEPTH + sw) * FR_LS + wv * 3328;
#pragma unroll
            for (int q = 0; q < 2; ++q) {
                const int ul = q * 4 + quad;
                const int ug = u0 + ul;
                float z[4];
#pragma unroll
                for (int g = 0; g < 4; ++g) {
                    const int gb = (g * 8 + ul) * 4;
                    z[g] = zlds[wvz + b_loc * 33 + g * 8 + ul]
                         + gc[gb + 0] + x0 * gc[gb + 1] + x1 * gc[gb + 2] + x2 * gc[gb + 3];
                }
                const float cp = cst[q];
                const float ig = sig_(z[0] + gc[128 + ul * 3 + 0] * cp);
                const float fg = sig_(z[1] + gc[128 + ul * 3 + 1] * cp);
                const float cn = fg * cp + ig * tanh_(z[2]);
                const float og = sig_(z[3] + gc[128 + ul * 3 + 2] * cn);
                cst[q] = cn;
                const float hv = og * tanh_(cn);
                const float pv = __shfl_xor(hv, 16, 64);
                if ((quad & 1) == 0) {
                    const unsigned pw_ = ((f16u(hv) & ~1u) | pI) | (f16u(pv) << 16);
                    const int u = ug;                    // even
                    agstoreu(fr_dst + (u >> 5) * 256 + ((u & 7) >> 1) * 64
                                    + ((u >> 3) & 3) * 16 + b_loc, pw_);
                }
            }
        } else if (layer < 3) {
            unsigned* fr_dst = frag0 + (size_t)(layer * DEPTH + sw) * FR_LS + wv * 3328;
            const int ul = quad;
            float z[4];
#pragma unroll
            for (int g = 0; g < 4; ++g)
                z[g] = zlds[wvz + b_loc * 33 + g * 4 + ul] + gc[g * 4 + ul];
            const float cp = cst[0];
            const float ig = sig_(z[0] + gc[16 + ul * 3 + 0] * cp);
            const float fg = sig_(z[1] + gc[16 + ul * 3 + 1] * cp);
            const float cn = fg * cp + ig * tanh_(z[2]);
            const float og = sig_(z[3] + gc[16 + ul * 3 + 2] * cn);
            cst[0] = cn;
            const float hv = og * tanh_(cn);
            const float pv = __shfl_xor(hv, 16, 64);
            if ((ul & 1) == 0) {
                const unsigned pw_ = ((f16u(hv) & ~1u) | pI) | (f16u(pv) << 16);
                const int u = u0 + ul;                   // even
                agstoreu(fr_dst + (u >> 5) * 256 + ((u & 7) >> 1) * 64
                                + ((u >> 3) & 3) * 16 + b_loc, pw_);
            }
        }

        // ---- per-wave progress bump (single writer per counter; certifies READS) ----
        if (lane == 0) {
            if      (blk == 50)  agstoreu(Dc + (0 * 4 + wv) * 32, (unsigned)(t + 1));
            else if (blk == 150) agstoreu(Dc + (1 * 4 + wv) * 32, (unsigned)(t + 1));
            else if (blk == 250) agstoreu(Dc + (2 * 4 + wv) * 32, (unsigned)(t + 1));
        }
        // no drain, no barrier, no RMW
    }
}

template<int DEPTH>
static void launch_variant(void* const* d_in, float* out, unsigned* ws, hipStream_t stream) {
    const float* x    = (const float*)d_in[0];
    const float* Wx0  = (const float*)d_in[1];
    const float* Wx1  = (const float*)d_in[2];
    const float* Wx2  = (const float*)d_in[3];
    const float* Wh   = (const float*)d_in[4];
    const float* bias = (const float*)d_in[5];
    const float* pi   = (const float*)d_in[6];
    const float* pf   = (const float*)d_in[7];
    const float* po   = (const float*)d_in[8];
    const float* Wd   = (const float*)d_in[9];
    const float* bd   = (const float*)d_in[10];
    void* args[] = { (void*)&x, (void*)&Wx0, (void*)&Wx1, (void*)&Wx2, (void*)&Wh,
                     (void*)&bias, (void*)&pi, (void*)&pf, (void*)&po,
                     (void*)&Wd, (void*)&bd, (void*)&out, (void*)&ws };
    hipError_t err = hipLaunchCooperativeKernel((void*)lstm_pb<DEPTH>,
                                                dim3(251), dim3(256), args, 0, stream);
    if (err != hipSuccess)
        hipLaunchKernelGGL((lstm_pb<DEPTH>), dim3(251), dim3(256), 0, stream,
                           x, Wx0, Wx1, Wx2, Wh, bias, pi, pf, po, Wd, bd, out, ws);
}

extern "C" void kernel_launch(void* const* d_in, const int* in_sizes, int n_in,
                              void* d_out, int out_size, void* d_ws, size_t ws_size,
                              hipStream_t stream) {
    float* out = (float*)d_out;
    unsigned* ws = (unsigned*)d_ws;

    auto fragbytes = [](int depth) -> size_t { return (size_t)3 * depth * FR_LS * 4; };

    if (ws_size >= 2048 + fragbytes(8)) {            // ~1.28 MB
        hipMemsetAsync(d_ws, 0, 2048, stream);                              // counters = 0
        hipMemsetAsync((char*)d_ws + 2048, 0xFF, fragbytes(8), stream);     // frags: parity-1
        launch_variant<8>(d_in, out, ws, stream);
    } else {                                          // ~0.64 MB
        hipMemsetAsync(d_ws, 0, 2048, stream);
        hipMemsetAsync((char*)d_ws + 2048, 0xFF, fragbytes(4), stream);
        launch_variant<4>(d_in, out, ws, stream);
    }
}

// Round 10
// 3307.581 us; speedup vs baseline: 1.3153x; 1.3153x over previous
//
#include <hip/hip_runtime.h>
#include <hip/hip_fp16.h>
#include <math.h>

#define B_ 64
#define T_ 700
#define U_ 400
#define FR_LS 13312                   // dwords per (layer,slot): 4 bt x 13 kc x 256
#define NFR 64                        // flag ring slots (accumulating targets)
#define CP 2                          // flag copies
#define FW (NFR * 4 * CP * 32)        // dwords per flag array

typedef _Float16 half8 __attribute__((ext_vector_type(8)));
typedef float float4v __attribute__((ext_vector_type(4)));

union AFrag { unsigned u[4]; half8 h; };

__device__ __forceinline__ unsigned agloadu(const unsigned* p) {
    return __hip_atomic_load(p, __ATOMIC_RELAXED, __HIP_MEMORY_SCOPE_AGENT);
}
__device__ __forceinline__ void agstoreu(unsigned* p, unsigned v) {
    __hip_atomic_store(p, v, __ATOMIC_RELAXED, __HIP_MEMORY_SCOPE_AGENT);
}
__device__ __forceinline__ float sig_(float v) {
    return __builtin_amdgcn_rcpf(1.f + __expf(-v));
}
__device__ __forceinline__ float tanh_(float v) {
    return 1.f - 2.f * __builtin_amdgcn_rcpf(__expf(2.f * v) + 1.f);
}
__device__ __forceinline__ void waitge(const unsigned* f, unsigned target) {
    while (agloadu(f) < target) __builtin_amdgcn_s_sleep(2);
}
__device__ __forceinline__ unsigned f16u(float v) {
    union { _Float16 f; unsigned short s; } cv; cv.f = (_Float16)v; return (unsigned)cv.s;
}

// Parity-tagged own-edge read (R8-proven): sloppy 1-dword/lane probe, then batched
// verify over 13 chunks x 4 dwords. ABA-safe via wrap parity + lagged Dc bounds.
__device__ __forceinline__ void pollfrag13(const unsigned* __restrict__ base,
                                           const unsigned par,
                                           AFrag* __restrict__ a, const int lane)
{
    {
        const unsigned* pp = base + (lane % 13) * 256 + ((lane * 37) & 255);
        while (!__all((int)(((agloadu(pp) ^ par) & 1u) == 0u)))
            __builtin_amdgcn_s_sleep(1);
    }
    unsigned pend = 0x1FFFu;
    do {
#pragma unroll
        for (int ck = 0; ck < 13; ++ck) if ((pend >> ck) & 1) {
#pragma unroll
            for (int d = 0; d < 4; ++d)
                a[ck].u[d] = agloadu(base + ck * 256 + d * 64 + lane);
        }
#pragma unroll
        for (int ck = 0; ck < 13; ++ck) if ((pend >> ck) & 1) {
            const unsigned m = (a[ck].u[0] ^ par) | (a[ck].u[1] ^ par)
                             | (a[ck].u[2] ^ par) | (a[ck].u[3] ^ par);
            if (__all((int)((m & 1u) == 0u))) pend &= ~(1u << ck);
        }
        if (pend) __builtin_amdgcn_s_sleep(1);
    } while (pend);
}

//  blocks 0..49   : layer 0, 8 units (32 gate-cols), A = h0[t-1]
//  blocks 50..99  : layer 1, 8 units, A = [h0[t] ; h1[t-1]]
//  blocks 100..149: layer 2, 8 units, A = [h1[t] ; h2[t-1]]
//  block 150      : output projection h2[t] @ Wd + bd
//  Own-layer edge: parity-tagged data poll. Input edge: per-wave drain-certified
//  flags (ring of NFR slots, accumulating target 50*(t/NFR+1)). Anti-overwrite:
//  per-wave single-writer lagged counters Dc. NO per-step __syncthreads.
template<int DEPTH>
__global__ void __launch_bounds__(256, 1)
lstm_pw(const float* __restrict__ x,
        const float* __restrict__ Wx0,
        const float* __restrict__ Wx1,
        const float* __restrict__ Wx2,
        const float* __restrict__ Wh,
        const float* __restrict__ bias,
        const float* __restrict__ pi,
        const float* __restrict__ pf,
        const float* __restrict__ po,
        const float* __restrict__ Wd,
        const float* __restrict__ bd,
        float* __restrict__ out,
        unsigned* __restrict__ ws)
{
    __shared__ alignas(16) _Float16 wlds[52 * 512];   // 53.2 KB B-frags [ck][lane][8]
    __shared__ alignas(16) float zlds[4 * 528];       // 8.4 KB per-wave z tiles
    __shared__ float gc[160];                          // gate constants

    unsigned* Dc    = ws;                 // [3][4] per-wave lagged counters (stride 32)
    unsigned* F0    = ws + 512;
    unsigned* F1    = F0 + FW;
    unsigned* F2    = F1 + FW;
    unsigned* frag0 = ws + 512 + 3 * FW;  // [3][DEPTH][FR_LS], init 0xFF (parity 1)

    const int blk  = blockIdx.x;
    const int tid  = threadIdx.x;
    const int lane = tid & 63;
    const int wv   = tid >> 6;
    const int cpi  = blk & (CP - 1);

    int layer, u0;
    if      (blk < 50)  { layer = 0; u0 = blk * 8; }
    else if (blk < 100) { layer = 1; u0 = (blk - 50) * 8; }
    else if (blk < 150) { layer = 2; u0 = (blk - 100) * 8; }
    else                { layer = 3; u0 = 0; }

    const bool padw = (blk == 49) || (blk == 99) || (blk == 149);

    // ---- one-time weight staging into LDS (B-fragment order) ----
    {
        if (layer == 0) {
            for (int i = tid; i < 26 * 64; i += 256) {
                const int ln = i & 63, ck = i >> 6;
                const int q = ln >> 4, nn = ln & 15;
                float vals[8];
#pragma unroll
                for (int j = 0; j < 8; ++j) {
                    const int kc = ck % 13;
                    const int k = kc * 32 + q * 8 + j;
                    float v = 0.f;
                    if (k < 400) {
                        const int col32 = (ck / 13) * 16 + nn;
                        const int gcol = (col32 >> 3) * U_ + u0 + (col32 & 7);
                        v = Wh[(size_t)k * 1600 + gcol];
                    }
                    vals[j] = v;
                }
#pragma unroll
                for (int j = 0; j < 8; ++j)
                    wlds[ck * 512 + ln * 8 + j] = (_Float16)vals[j];
            }
            if (tid < 128) {
                const int col32 = tid >> 2, comp = tid & 3;
                const int gcol = (col32 >> 3) * U_ + u0 + (col32 & 7);
                gc[tid] = (comp == 0) ? bias[gcol] : Wx0[(size_t)(comp - 1) * 1600 + gcol];
            } else if (tid < 152) {
                const int idx = tid - 128, ul = idx / 3, j = idx - ul * 3;
                const float* pp = (j == 0) ? pi : (j == 1) ? pf : po;
                gc[tid] = pp[u0 + ul];
            }
        } else if (layer < 3) {
            const float* __restrict__ Wxl = (layer == 1) ? Wx1 : Wx2;
            for (int i = tid; i < 52 * 64; i += 256) {
                const int ln = i & 63, ckk = i >> 6;
                const int q = ln >> 4, nn = ln & 15;
                const int tile = ckk / 26, c26 = ckk % 26;
                const int kc = c26 % 13;
                const bool iswh = (c26 >= 13);
                const int col32 = tile * 16 + nn;
                const int gcol = (col32 >> 3) * U_ + u0 + (col32 & 7);
                float vals[8];
#pragma unroll
                for (int j = 0; j < 8; ++j) {
                    const int k = kc * 32 + q * 8 + j;
                    float v = 0.f;
                    if (k < 400)
                        v = iswh ? Wh[((size_t)layer * U_ + k) * 1600 + gcol]
                                 : Wxl[(size_t)k * 1600 + gcol];
                    vals[j] = v;
                }
#pragma unroll
                for (int j = 0; j < 8; ++j)
                    wlds[ckk * 512 + ln * 8 + j] = (_Float16)vals[j];
            }
            if (tid < 32) {   // bias per gate-col n = g*8+ul
                const int gcol = (tid >> 3) * U_ + u0 + (tid & 7);
                gc[tid] = bias[layer * 1600 + gcol];
            } else if (tid < 56) {
                const int idx = tid - 32, ul = idx / 3, j = idx - ul * 3;
                const float* pp = (j == 0) ? pi : (j == 1) ? pf : po;
                gc[tid] = pp[layer * U_ + u0 + ul];
            }
        } else {
            for (int i = tid; i < 13 * 64; i += 256) {
                const int ln = i & 63, ck = i >> 6;
                const int q = ln >> 4, nn = ln & 15;
                float vals[8];
#pragma unroll
                for (int j = 0; j < 8; ++j) {
                    const int k = ck * 32 + q * 8 + j;
                    vals[j] = (k < 400 && nn < 3) ? Wd[k * 3 + nn] : 0.f;
                }
#pragma unroll
                for (int j = 0; j < 8; ++j)
                    wlds[ck * 512 + ln * 8 + j] = (_Float16)vals[j];
            }
            if (tid < 3) gc[tid] = bd[tid];
        }
    }
    __syncthreads();   // the ONLY barrier — steady loop is barrier-free

    const int wvz   = wv * 528;
    const int b_loc = lane & 15;
    const int quad  = lane >> 4;
    float cst[2] = {0.f, 0.f};

    for (int t = 0; t < T_; ++t) {
        const int sw = t % DEPTH;
        const int sr = (t + DEPTH - 1) % DEPTH;
        const unsigned pI = (unsigned)((t / DEPTH) & 1);
        const unsigned pO = (unsigned)(((t - 1) / DEPTH) & 1);
        const unsigned ftarget = (unsigned)((t >> 6) + 1) * 50u;
        const int fidx = (((t & 63) * 4 + wv) * CP + cpi) * 32;

        // x prefetch (L0)
        float x0, x1, x2;
        if (layer == 0) {
            const size_t xb = (size_t)(wv * 16 + b_loc) * T_ + t;
            x0 = x[xb * 3 + 0]; x1 = x[xb * 3 + 1]; x2 = x[xb * 3 + 2];
        }

        // ---- input edge: per-wave drain-certified flag, then batch load ----
        AFrag ainp[13];
        if (layer == 1 || layer == 2) {
            if (lane == 0) waitge(((layer == 1) ? F0 : F1) + fidx, ftarget);
            asm volatile("" ::: "memory");
            const unsigned* frI = frag0 + (size_t)((layer - 1) * DEPTH + sw) * FR_LS + wv * 3328;
#pragma unroll
            for (int kc = 0; kc < 13; ++kc)
#pragma unroll
                for (int d = 0; d < 4; ++d)
                    ainp[kc].u[d] = agloadu(frI + kc * 256 + d * 64 + lane);
        }

        // ---- own edge: parity poll (overlaps the in-flight input loads) ----
        AFrag aown[13];
        if (layer == 3) {
            if (lane == 0) waitge(F2 + fidx, ftarget);
            asm volatile("" ::: "memory");
            const unsigned* frI = frag0 + (size_t)(2 * DEPTH + sw) * FR_LS + wv * 3328;
#pragma unroll
            for (int kc = 0; kc < 13; ++kc)
#pragma unroll
                for (int d = 0; d < 4; ++d)
                    aown[kc].u[d] = agloadu(frI + kc * 256 + d * 64 + lane);
        } else if (t >= 1) {
            pollfrag13(frag0 + (size_t)(layer * DEPTH + sr) * FR_LS + wv * 3328, pO, aown, lane);
        } else {
#pragma unroll
            for (int kc = 0; kc < 13; ++kc)
#pragma unroll
                for (int d = 0; d < 4; ++d) aown[kc].u[d] = 0u;
        }
        asm volatile("" ::: "memory");

        // ---- MFMA ----
        if (layer == 0) {
            float4v acc0 = {0.f, 0.f, 0.f, 0.f}, acc1 = {0.f, 0.f, 0.f, 0.f};
#pragma unroll
            for (int kc = 0; kc < 13; ++kc) {
                const half8 w0 = *(const half8*)&wlds[kc * 512 + lane * 8];
                const half8 w1 = *(const half8*)&wlds[(13 + kc) * 512 + lane * 8];
                acc0 = __builtin_amdgcn_mfma_f32_16x16x32_f16(aown[kc].h, w0, acc0, 0, 0, 0);
                acc1 = __builtin_amdgcn_mfma_f32_16x16x32_f16(aown[kc].h, w1, acc1, 0, 0, 0);
            }
#pragma unroll
            for (int r = 0; r < 4; ++r) {
                zlds[wvz + (quad * 4 + r) * 33 + b_loc] = acc0[r];
                zlds[wvz + (quad * 4 + r) * 33 + 16 + b_loc] = acc1[r];
            }
        } else if (layer < 3) {
            float4v acc0 = {0.f, 0.f, 0.f, 0.f}, acc1 = {0.f, 0.f, 0.f, 0.f};
#pragma unroll
            for (int kc = 0; kc < 13; ++kc) {
                const half8 wA0 = *(const half8*)&wlds[kc * 512 + lane * 8];
                const half8 wB0 = *(const half8*)&wlds[(13 + kc) * 512 + lane * 8];
                const half8 wA1 = *(const half8*)&wlds[(26 + kc) * 512 + lane * 8];
                const half8 wB1 = *(const half8*)&wlds[(39 + kc) * 512 + lane * 8];
                acc0 = __builtin_amdgcn_mfma_f32_16x16x32_f16(ainp[kc].h, wA0, acc0, 0, 0, 0);
                acc1 = __builtin_amdgcn_mfma_f32_16x16x32_f16(ainp[kc].h, wA1, acc1, 0, 0, 0);
                acc0 = __builtin_amdgcn_mfma_f32_16x16x32_f16(aown[kc].h, wB0, acc0, 0, 0, 0);
                acc1 = __builtin_amdgcn_mfma_f32_16x16x32_f16(aown[kc].h, wB1, acc1, 0, 0, 0);
            }
#pragma unroll
            for (int r = 0; r < 4; ++r) {
                zlds[wvz + (quad * 4 + r) * 33 + b_loc] = acc0[r];
                zlds[wvz + (quad * 4 + r) * 33 + 16 + b_loc] = acc1[r];
            }
        } else {
            float4v acc = {0.f, 0.f, 0.f, 0.f};
#pragma unroll
            for (int kc = 0; kc < 13; ++kc) {
                const half8 w0 = *(const half8*)&wlds[kc * 512 + lane * 8];
                acc = __builtin_amdgcn_mfma_f32_16x16x32_f16(aown[kc].h, w0, acc, 0, 0, 0);
            }
            if (b_loc < 3) {
#pragma unroll
                for (int r = 0; r < 4; ++r)
                    out[((size_t)(wv * 16 + quad * 4 + r) * T_ + t) * 3 + b_loc] = acc[r] + gc[b_loc];
            }
        }

        // ---- per-wave lagged anti-overwrite (single-writer counters) ----
        if (layer < 3 && lane == 0 && t >= DEPTH)
            waitge(Dc + (layer * 4 + wv) * 32, (unsigned)(t - DEPTH + 2));
        asm volatile("" ::: "memory");

        // ---- K-pad rewrite (per-wave, last block of each layer) ----
        if (padw) {
            unsigned* fd = frag0 + (size_t)(layer * DEPTH + sw) * FR_LS + wv * 3328 + 12 * 256;
            agstoreu(fd + quad * 64 + 32 + b_loc, pI);   // q=2
            agstoreu(fd + quad * 64 + 48 + b_loc, pI);   // q=3
        }

        // ---- gates (fp32, same-wave zlds transpose: no barrier) + h store ----
        if (layer < 3) {
            unsigned* fr_dst = frag0 + (size_t)(layer * DEPTH + sw) * FR_LS + wv * 3328;
#pragma unroll
            for (int q = 0; q < 2; ++q) {
                const int ul = q * 4 + quad;
                float z[4];
#pragma unroll
                for (int g = 0; g < 4; ++g) {
                    const float zs = zlds[wvz + b_loc * 33 + g * 8 + ul];
                    if (layer == 0) {
                        const int gb = (g * 8 + ul) * 4;
                        z[g] = zs + gc[gb + 0] + x0 * gc[gb + 1] + x1 * gc[gb + 2] + x2 * gc[gb + 3];
                    } else {
                        z[g] = zs + gc[g * 8 + ul];
                    }
                }
                const int pbase = (layer == 0) ? 128 : 32;
                const float cp = cst[q];
                const float ig = sig_(z[0] + gc[pbase + ul * 3 + 0] * cp);
                const float fg = sig_(z[1] + gc[pbase + ul * 3 + 1] * cp);
                const float cn = fg * cp + ig * tanh_(z[2]);
                const float og = sig_(z[3] + gc[pbase + ul * 3 + 2] * cn);
                cst[q] = cn;
                const float hv = og * tanh_(cn);
                const float pv = __shfl_xor(hv, 16, 64);
                if ((quad & 1) == 0) {
                    const unsigned pw_ = ((f16u(hv) & ~1u) | pI) | (f16u(pv) << 16);
                    const int u = u0 + ul;               // even
                    agstoreu(fr_dst + (u >> 5) * 256 + ((u & 7) >> 1) * 64
                                    + ((u >> 3) & 3) * 16 + b_loc, pw_);
                }
            }
        }

        // ---- per-wave publish: drain own stores, bump flag copies; bump Dc ----
        if (layer < 3) {
            asm volatile("s_waitcnt vmcnt(0)" ::: "memory");
            unsigned* f = (layer == 0) ? F0 : (layer == 1) ? F1 : F2;
            if (lane < CP)
                __hip_atomic_fetch_add(f + (((t & 63) * 4 + wv) * CP + lane) * 32, 1u,
                                       __ATOMIC_RELAXED, __HIP_MEMORY_SCOPE_AGENT);
        }
        if (lane == 0) {
            if      (blk == 50)  agstoreu(Dc + (0 * 4 + wv) * 32, (unsigned)(t + 1));
            else if (blk == 100) agstoreu(Dc + (1 * 4 + wv) * 32, (unsigned)(t + 1));
            else if (blk == 150) agstoreu(Dc + (2 * 4 + wv) * 32, (unsigned)(t + 1));
        }
    }
}

template<int DEPTH>
static void launch_variant(void* const* d_in, float* out, unsigned* ws, hipStream_t stream) {
    const float* x    = (const float*)d_in[0];
    const float* Wx0  = (const float*)d_in[1];
    const float* Wx1  = (const float*)d_in[2];
    const float* Wx2  = (const float*)d_in[3];
    const float* Wh   = (const float*)d_in[4];
    const float* bias = (const float*)d_in[5];
    const float* pi   = (const float*)d_in[6];
    const float* pf   = (const float*)d_in[7];
    const float* po   = (const float*)d_in[8];
    const float* Wd   = (const float*)d_in[9];
    const float* bd   = (const float*)d_in[10];
    void* args[] = { (void*)&x, (void*)&Wx0, (void*)&Wx1, (void*)&Wx2, (void*)&Wh,
                     (void*)&bias, (void*)&pi, (void*)&pf, (void*)&po,
                     (void*)&Wd, (void*)&bd, (void*)&out, (void*)&ws };
    hipError_t err = hipLaunchCooperativeKernel((void*)lstm_pw<DEPTH>,
                                                dim3(151), dim3(256), args, 0, stream);
    if (err != hipSuccess)
        hipLaunchKernelGGL((lstm_pw<DEPTH>), dim3(151), dim3(256), 0, stream,
                           x, Wx0, Wx1, Wx2, Wh, bias, pi, pf, po, Wd, bd, out, ws);
}

extern "C" void kernel_launch(void* const* d_in, const int* in_sizes, int n_in,
                              void* d_out, int out_size, void* d_ws, size_t ws_size,
                              hipStream_t stream) {
    float* out = (float*)d_out;
    unsigned* ws = (unsigned*)d_ws;

    const size_t hdr = (size_t)(512 + 3 * FW) * 4;            // Dc + flag arrays
    auto fragbytes = [](int depth) -> size_t { return (size_t)3 * depth * FR_LS * 4; };

    if (ws_size >= hdr + fragbytes(8)) {            // ~1.48 MB
        hipMemsetAsync(d_ws, 0, hdr, stream);                          // counters+flags = 0
        hipMemsetAsync((char*)d_ws + hdr, 0xFF, fragbytes(8), stream); // frags: parity-1
        launch_variant<8>(d_in, out, ws, stream);
    } else {                                         // ~0.84 MB
        hipMemsetAsync(d_ws, 0, hdr, stream);
        hipMemsetAsync((char*)d_ws + hdr, 0xFF, fragbytes(4), stream);
        launch_variant<4>(d_in, out, ws, stream);
    }
}